// Round 1
// baseline (1361.475 us; speedup 1.0000x reference)
//
#include <hip/hip_runtime.h>

#define NNODES 49152
#define NB 4
#define NE 393216
#define MTOT (NB*NNODES)
#define EPS 1e-5f

#define FMA4(ACCV, AS, BV) do { (ACCV).x += (AS)*(BV).x; (ACCV).y += (AS)*(BV).y; (ACCV).z += (AS)*(BV).z; (ACCV).w += (AS)*(BV).w; } while(0)

// ---------------- setup kernels ----------------
__global__ __launch_bounds__(256) void k_deg_cnt(const int* __restrict__ row,
    const float* __restrict__ w, float* __restrict__ deg, int* __restrict__ cnt)
{
    int e = blockIdx.x*256 + threadIdx.x;
    if (e >= NE) return;
    int r = row[e];
    atomicAdd(&deg[r], w[e]);
    atomicAdd(&cnt[r], 1);
}

__global__ __launch_bounds__(256) void k_dinv(const float* __restrict__ deg, float* __restrict__ dinv)
{
    int i = blockIdx.x*256 + threadIdx.x;
    if (i >= NNODES) return;
    float d = deg[i];
    dinv[i] = (d > 0.0f) ? rsqrtf(fmaxf(d, EPS)) : 0.0f;
}

__global__ __launch_bounds__(1024) void k_scan(const int* __restrict__ cnt, int* __restrict__ rowptr)
{
    __shared__ int ssum[1024];
    const int CH = NNODES/1024; // 48
    int t = threadIdx.x;
    int base = t*CH;
    int loc[CH];
    int s = 0;
    #pragma unroll
    for (int i = 0; i < CH; ++i) { loc[i] = s; s += cnt[base+i]; }
    ssum[t] = s;
    __syncthreads();
    for (int off = 1; off < 1024; off <<= 1) {
        int v = ssum[t];
        int add = (t >= off) ? ssum[t-off] : 0;
        __syncthreads();
        ssum[t] = v + add;
        __syncthreads();
    }
    int prefix = (t == 0) ? 0 : ssum[t-1];
    #pragma unroll
    for (int i = 0; i < CH; ++i) rowptr[base+i] = prefix + loc[i];
    if (t == 0) rowptr[NNODES] = ssum[1023];
}

__global__ __launch_bounds__(256) void k_fill(const int* __restrict__ row, const int* __restrict__ col,
    const float* __restrict__ w, const float* __restrict__ dinv,
    const int* __restrict__ rowptr, int* __restrict__ fill,
    int* __restrict__ ecol, float* __restrict__ ea)
{
    int e = blockIdx.x*256 + threadIdx.x;
    if (e >= NE) return;
    int r = row[e], c = col[e];
    int pos = rowptr[r] + atomicAdd(&fill[r], 1);
    ecol[pos] = c;
    ea[pos] = w[e] * dinv[r] * dinv[c];
}

// Build Bc [Fin][192] = [W0-W2 | W1 | W2] from W [3][Fin][64]
__global__ __launch_bounds__(256) void k_buildB(const float* __restrict__ W, float* __restrict__ Bc, int Fin)
{
    int i = blockIdx.x*256 + threadIdx.x;
    if (i >= Fin*192) return;
    int f = i/192, j = i%192;
    float v;
    if (j < 64)       v = W[0*Fin*64 + f*64 + j] - W[2*Fin*64 + f*64 + j];
    else if (j < 128) v = W[1*Fin*64 + f*64 + (j-64)];
    else              v = W[2*Fin*64 + f*64 + (j-128)];
    Bc[i] = v;
}

// ---------------- GEMM: C[M,BN_] = concat_K(A0|A1|A2)[M,K] @ B[K,BN_] ----------------
// A parts each have row stride Kper; B row stride BN_; C row stride BN_.
template<int BN_>
__global__ __launch_bounds__(256) void k_gemm(const float* __restrict__ A0,
    const float* __restrict__ A1, const float* __restrict__ A2,
    int Kper, int K, const float* __restrict__ Bm, float* __restrict__ Cm, int accum)
{
    const int SEG = BN_/64;
    __shared__ float As[32][68];
    __shared__ float Bs[32][BN_];
    int tid = threadIdx.x;
    long m0 = (long)blockIdx.x * 64;
    int tr = tid >> 4, tc = tid & 15;
    float4 acc[4][SEG];
    #pragma unroll
    for (int i = 0; i < 4; ++i)
        #pragma unroll
        for (int s2 = 0; s2 < SEG; ++s2) acc[i][s2] = make_float4(0.f,0.f,0.f,0.f);

    int ar = tid >> 3;          // 0..31
    int akc = (tid & 7) * 4;    // 0..28

    for (int kt = 0; kt < K; kt += 32) {
        int part = kt / Kper;
        const float* Ap = (part == 0) ? A0 : ((part == 1) ? A1 : A2);
        int kcol = kt - part * Kper;
        #pragma unroll
        for (int h = 0; h < 2; ++h) {
            int r = ar + h*32;
            float4 v = *(const float4*)(Ap + (m0 + r) * (long)Kper + kcol + akc);
            As[akc+0][r] = v.x; As[akc+1][r] = v.y; As[akc+2][r] = v.z; As[akc+3][r] = v.w;
        }
        #pragma unroll
        for (int it = 0; it < BN_/32; ++it) {
            int fid = tid + it*256;
            int r = fid / (BN_/4), c4 = fid % (BN_/4);
            *(float4*)&Bs[r][c4*4] = *(const float4*)(Bm + (long)(kt + r) * BN_ + c4*4);
        }
        __syncthreads();
        #pragma unroll
        for (int kk = 0; kk < 32; ++kk) {
            float4 av = *(const float4*)&As[kk][tr*4];
            #pragma unroll
            for (int s2 = 0; s2 < SEG; ++s2) {
                float4 bv = *(const float4*)&Bs[kk][s2*64 + tc*4];
                FMA4(acc[0][s2], av.x, bv);
                FMA4(acc[1][s2], av.y, bv);
                FMA4(acc[2][s2], av.z, bv);
                FMA4(acc[3][s2], av.w, bv);
            }
        }
        __syncthreads();
    }
    #pragma unroll
    for (int i = 0; i < 4; ++i) {
        long crow = m0 + tr*4 + i;
        #pragma unroll
        for (int s2 = 0; s2 < SEG; ++s2) {
            float* cp = Cm + crow * BN_ + s2*64 + tc*4;
            float4 r2 = acc[i][s2];
            if (accum) { float4 o = *(const float4*)cp; r2.x += o.x; r2.y += o.y; r2.z += o.z; r2.w += o.w; }
            *(float4*)cp = r2;
        }
    }
}

// ---------------- propagation (CSR gather): dst = beta*base + alpha*sum_e a[e]*src[col[e]] ----------------
// all feature widths are 64; strides/offsets in floats. base may be nullptr (beta ignored).
__global__ __launch_bounds__(256) void k_prop(
    const int* __restrict__ rowptr, const int* __restrict__ ecol, const float* __restrict__ ea,
    const float* __restrict__ src, int sstride, int soff,
    const float* __restrict__ basep, int bstride, int boff, float beta,
    float* __restrict__ dst, int dstride, int doff, float alpha)
{
    int g = blockIdx.x*16 + (threadIdx.x >> 4);
    int q = threadIdx.x & 15;
    int e0 = rowptr[g], e1 = rowptr[g+1];
    float4 acc[4];
    #pragma unroll
    for (int b = 0; b < 4; ++b) acc[b] = make_float4(0.f,0.f,0.f,0.f);
    for (int e = e0; e < e1; ++e) {
        int c = ecol[e];
        float a = ea[e];
        #pragma unroll
        for (int b = 0; b < 4; ++b) {
            const float4 v = *(const float4*)(src + ((long)b*NNODES + c) * sstride + soff + q*4);
            FMA4(acc[b], a, v);
        }
    }
    #pragma unroll
    for (int b = 0; b < 4; ++b) {
        float4 r2;
        r2.x = alpha*acc[b].x; r2.y = alpha*acc[b].y; r2.z = alpha*acc[b].z; r2.w = alpha*acc[b].w;
        if (basep) {
            const float4 bb = *(const float4*)(basep + ((long)b*NNODES + g) * bstride + boff + q*4);
            r2.x += beta*bb.x; r2.y += beta*bb.y; r2.z += beta*bb.z; r2.w += beta*bb.w;
        }
        *(float4*)(dst + ((long)b*NNODES + g) * dstride + doff + q*4) = r2;
    }
}

// ---------------- instance-norm stats / finalize / apply ----------------
template<int C_>
__global__ __launch_bounds__(256) void k_stats(const float* __restrict__ y, int stride,
    float* __restrict__ sum, float* __restrict__ sumsq)
{
    const int RPI = 256 / C_;
    int b = blockIdx.y;
    int c = threadIdx.x % C_;
    int rsub = threadIdx.x / C_;
    int r0 = blockIdx.x * 256;
    float s = 0.f, ss = 0.f;
    for (int r = r0 + rsub; r < r0 + 256; r += RPI) {
        float v = y[((long)b*NNODES + r) * stride + c];
        s += v; ss += v*v;
    }
    __shared__ float ls[256], lss[256];
    ls[threadIdx.x] = s; lss[threadIdx.x] = ss;
    __syncthreads();
    if (rsub == 0) {
        #pragma unroll
        for (int k = 1; k < RPI; ++k) { s += ls[c + k*C_]; ss += lss[c + k*C_]; }
        atomicAdd(&sum[b*256 + c], s);
        atomicAdd(&sumsq[b*256 + c], ss);
    }
}

__global__ __launch_bounds__(256) void k_finalize(const float* __restrict__ sum,
    const float* __restrict__ sumsq, float* __restrict__ mean, float* __restrict__ rs, int C_)
{
    int i = blockIdx.x*256 + threadIdx.x;
    if (i >= NB*256) return;
    int c = i % 256;
    if (c >= C_) return;
    float m = sum[i] / (float)NNODES;
    float v = sumsq[i] / (float)NNODES - m*m;
    mean[i] = m;
    rs[i] = rsqrtf(v + EPS);
}

// X[bn*64+c] = relu((U[bn*192+c]-mean)*rs), c in [0,64)
__global__ __launch_bounds__(256) void k_normrelu(const float* __restrict__ U,
    const float* __restrict__ mean, const float* __restrict__ rs, float* __restrict__ X)
{
    long idx = (long)blockIdx.x*256 + threadIdx.x;  // MTOT*16 threads
    long bn = idx >> 4;
    int q = (int)(idx & 15);
    int b = (int)(bn / NNODES);
    float4 v = *(const float4*)(U + bn*192 + q*4);
    float4 m = *(const float4*)(mean + b*256 + q*4);
    float4 r_ = *(const float4*)(rs + b*256 + q*4);
    float4 o;
    o.x = fmaxf((v.x-m.x)*r_.x, 0.f);
    o.y = fmaxf((v.y-m.y)*r_.y, 0.f);
    o.z = fmaxf((v.z-m.z)*r_.z, 0.f);
    o.w = fmaxf((v.w-m.w)*r_.w, 0.f);
    *(float4*)(X + bn*64 + q*4) = o;
}

// Y = relu((Y-mean)*rs) + x   (in-place over d_out, [M,256])
__global__ __launch_bounds__(256) void k_final(float* __restrict__ Y,
    const float* __restrict__ x, const float* __restrict__ mean, const float* __restrict__ rs)
{
    long idx = (long)blockIdx.x*256 + threadIdx.x;  // MTOT*64 threads
    long bn = idx >> 6;
    int q = (int)(idx & 63);
    int b = (int)(bn / NNODES);
    float4 v = *(const float4*)(Y + bn*256 + q*4);
    float4 m = *(const float4*)(mean + b*256 + q*4);
    float4 r_ = *(const float4*)(rs + b*256 + q*4);
    float4 xv = *(const float4*)(x + bn*256 + q*4);
    float4 o;
    o.x = fmaxf((v.x-m.x)*r_.x, 0.f) + xv.x;
    o.y = fmaxf((v.y-m.y)*r_.y, 0.f) + xv.y;
    o.z = fmaxf((v.z-m.z)*r_.z, 0.f) + xv.z;
    o.w = fmaxf((v.w-m.w)*r_.w, 0.f) + xv.w;
    *(float4*)(Y + bn*256 + q*4) = o;
}

__global__ __launch_bounds__(256) void k_negate(float* __restrict__ X)
{
    long idx = (long)blockIdx.x*256 + threadIdx.x;  // MTOT*16 threads
    float4 v = *(const float4*)(X + idx*4);
    v.x = -v.x; v.y = -v.y; v.z = -v.z; v.w = -v.w;
    *(float4*)(X + idx*4) = v;
}

extern "C" void kernel_launch(void* const* d_in, const int* in_sizes, int n_in,
                              void* d_out, int out_size, void* d_ws, size_t ws_size,
                              hipStream_t stream)
{
    const float* x  = (const float*)d_in[0];
    const int*   ei = (const int*)d_in[1];
    const float* ew = (const float*)d_in[2];
    const float* W1 = (const float*)d_in[3];
    const float* W2 = (const float*)d_in[5];
    const float* W3 = (const float*)d_in[7];
    const int* row = ei;
    const int* col = ei + NE;

    // ---- workspace bump allocator (1 KiB aligned) ----
    char* p = (char*)d_ws;
    size_t used = 0;
    auto alloc = [&](size_t bytes) -> void* {
        void* r = p + used;
        used += (bytes + 1023) & ~(size_t)1023;
        return r;
    };
    float* deg   = (float*)alloc((size_t)3*NNODES*4);   // deg | cnt | fill (one memset)
    int*   cnt   = (int*)(deg + NNODES);
    int*   fillc = (int*)(deg + 2*NNODES);
    float* dinv  = (float*)alloc((size_t)NNODES*4);
    int*   rowptr= (int*)alloc((size_t)(NNODES+1)*4);
    int*   ecol  = (int*)alloc((size_t)NE*4);
    float* ea    = (float*)alloc((size_t)NE*4);
    float* stats = (float*)alloc((size_t)2*NB*256*4);   // sum | sumsq
    float* sumb  = stats;
    float* sumsq = stats + NB*256;
    float* meanb = (float*)alloc((size_t)NB*256*4);
    float* rsb   = (float*)alloc((size_t)NB*256*4);
    float* Bc1   = (float*)alloc((size_t)256*192*4);
    float* Bc2   = (float*)alloc((size_t)64*192*4);
    size_t fixed = used;
    float* bufX  = (float*)alloc((size_t)MTOT*64*4);
    float* T1    = (float*)alloc((size_t)MTOT*64*4);
    size_t needB = used;
    float* T2    = (float*)alloc((size_t)MTOT*64*4);
    size_t needA = used;
    (void)fixed;

    bool pathA = ws_size >= needA;
    bool pathB = !pathA && ws_size >= needB;
    if (!pathA && !pathB) return; // insufficient workspace; will fail validation loudly

    float* U = (float*)d_out;   // [MTOT,192] scratch for layers 1-2 (151MB < 201MB)
    float* Y = (float*)d_out;   // [MTOT,256] final

    // ---- graph setup ----
    hipMemsetAsync(deg, 0, (size_t)3*NNODES*4, stream);
    k_deg_cnt<<<NE/256, 256, 0, stream>>>(row, ew, deg, cnt);
    k_dinv<<<NNODES/256, 256, 0, stream>>>(deg, dinv);
    k_scan<<<1, 1024, 0, stream>>>(cnt, rowptr);
    k_fill<<<NE/256, 256, 0, stream>>>(row, col, ew, dinv, rowptr, fillc, ecol, ea);
    k_buildB<<<256*192/256, 256, 0, stream>>>(W1, Bc1, 256);
    k_buildB<<<64*192/256, 256, 0, stream>>>(W2, Bc2, 64);

    // ---- layer 1: 256 -> 64 ----
    // U[:,0:64]=x@(W0-W2), U[:,64:128]=x@W1, U[:,128:192]=x@W2
    k_gemm<192><<<MTOT/64, 256, 0, stream>>>(x, nullptr, nullptr, 256, 256, Bc1, U, 0);
    // z = U1 - 2*S(U2)   (into col 64)
    k_prop<<<NNODES/16, 256, 0, stream>>>(rowptr, ecol, ea, U,192,128, U,192,64, 1.f, U,192,64, -2.f);
    // y = U0 - S(z)      (into col 0)
    k_prop<<<NNODES/16, 256, 0, stream>>>(rowptr, ecol, ea, U,192,64,  U,192,0,  1.f, U,192,0,  -1.f);
    hipMemsetAsync(stats, 0, (size_t)2*NB*256*4, stream);
    k_stats<64><<<dim3(NNODES/256, NB), 256, 0, stream>>>(U, 192, sumb, sumsq);
    k_finalize<<<NB, 256, 0, stream>>>(sumb, sumsq, meanb, rsb, 64);
    k_normrelu<<<MTOT*16/256, 256, 0, stream>>>(U, meanb, rsb, bufX);

    // ---- layer 2: 64 -> 64 ----
    k_gemm<192><<<MTOT/64, 256, 0, stream>>>(bufX, nullptr, nullptr, 64, 64, Bc2, U, 0);
    k_prop<<<NNODES/16, 256, 0, stream>>>(rowptr, ecol, ea, U,192,128, U,192,64, 1.f, U,192,64, -2.f);
    k_prop<<<NNODES/16, 256, 0, stream>>>(rowptr, ecol, ea, U,192,64,  U,192,0,  1.f, U,192,0,  -1.f);
    hipMemsetAsync(stats, 0, (size_t)2*NB*256*4, stream);
    k_stats<64><<<dim3(NNODES/256, NB), 256, 0, stream>>>(U, 192, sumb, sumsq);
    k_finalize<<<NB, 256, 0, stream>>>(sumb, sumsq, meanb, rsb, 64);
    k_normrelu<<<MTOT*16/256, 256, 0, stream>>>(U, meanb, rsb, bufX);   // bufX = X3

    // ---- layer 3: 64 -> 256 (propagate in input space) ----
    if (pathA) {
        // T1 = -S(X3) ; T2 = -X3 - 2*S(T1)
        k_prop<<<NNODES/16, 256, 0, stream>>>(rowptr, ecol, ea, bufX,64,0, nullptr,0,0, 0.f, T1,64,0, -1.f);
        k_prop<<<NNODES/16, 256, 0, stream>>>(rowptr, ecol, ea, T1,64,0, bufX,64,0, -1.f, T2,64,0, -2.f);
        // Y = X3@W3_0 + T1@W3_1 + T2@W3_2
        k_gemm<256><<<MTOT/64, 256, 0, stream>>>(bufX, T1, T2, 64, 192, W3, Y, 0);
    } else {
        // low-workspace: 3 accumulating GEMM passes, T2 built in-place over bufX
        k_gemm<256><<<MTOT/64, 256, 0, stream>>>(bufX, nullptr, nullptr, 64, 64, W3, Y, 0);
        k_prop<<<NNODES/16, 256, 0, stream>>>(rowptr, ecol, ea, bufX,64,0, nullptr,0,0, 0.f, T1,64,0, -1.f);
        k_gemm<256><<<MTOT/64, 256, 0, stream>>>(T1, nullptr, nullptr, 64, 64, W3 + 64*256, Y, 1);
        k_negate<<<MTOT*16/256, 256, 0, stream>>>(bufX);
        k_prop<<<NNODES/16, 256, 0, stream>>>(rowptr, ecol, ea, T1,64,0, bufX,64,0, 1.f, bufX,64,0, -2.f);
        k_gemm<256><<<MTOT/64, 256, 0, stream>>>(bufX, nullptr, nullptr, 64, 64, W3 + 2*64*256, Y, 1);
    }
    hipMemsetAsync(stats, 0, (size_t)2*NB*256*4, stream);
    k_stats<256><<<dim3(NNODES/256, NB), 256, 0, stream>>>(Y, 256, sumb, sumsq);
    k_finalize<<<NB, 256, 0, stream>>>(sumb, sumsq, meanb, rsb, 256);
    k_final<<<MTOT*64/256, 256, 0, stream>>>(Y, x, meanb, rsb);
}

// Round 2
// 698.875 us; speedup vs baseline: 1.9481x; 1.9481x over previous
//
#include <hip/hip_runtime.h>

#define NNODES 49152
#define NB 4
#define NE 393216
#define MTOT (NB*NNODES)
#define EPS 1e-5f

typedef __attribute__((ext_vector_type(8))) short s8v;   // 8 x bf16 (raw)
typedef __attribute__((ext_vector_type(4))) float f32x4;

__device__ inline float b2f(ushort u){ union{uint i; float f;} v; v.i = ((uint)u)<<16; return v.f; }
__device__ inline ushort f2b(float f){ union{float f; uint i;} v; v.f=f; uint r = v.i + 0x7fff + ((v.i>>16)&1); return (ushort)(r>>16); }

// ---------------- setup kernels ----------------
__global__ __launch_bounds__(256) void k_deg_cnt(const int* __restrict__ row,
    const float* __restrict__ w, float* __restrict__ deg, int* __restrict__ cnt)
{
    int e = blockIdx.x*256 + threadIdx.x;
    if (e >= NE) return;
    int r = row[e];
    atomicAdd(&deg[r], w[e]);
    atomicAdd(&cnt[r], 1);
}

__global__ __launch_bounds__(256) void k_dinv(const float* __restrict__ deg, float* __restrict__ dinv)
{
    int i = blockIdx.x*256 + threadIdx.x;
    if (i >= NNODES) return;
    float d = deg[i];
    dinv[i] = (d > 0.0f) ? rsqrtf(fmaxf(d, EPS)) : 0.0f;
}

__global__ __launch_bounds__(1024) void k_scan(const int* __restrict__ cnt, int* __restrict__ rowptr)
{
    __shared__ int ssum[1024];
    const int CH = NNODES/1024; // 48
    int t = threadIdx.x;
    int base = t*CH;
    int loc[CH];
    int s = 0;
    #pragma unroll
    for (int i = 0; i < CH; ++i) { loc[i] = s; s += cnt[base+i]; }
    ssum[t] = s;
    __syncthreads();
    for (int off = 1; off < 1024; off <<= 1) {
        int v = ssum[t];
        int add = (t >= off) ? ssum[t-off] : 0;
        __syncthreads();
        ssum[t] = v + add;
        __syncthreads();
    }
    int prefix = (t == 0) ? 0 : ssum[t-1];
    #pragma unroll
    for (int i = 0; i < CH; ++i) rowptr[base+i] = prefix + loc[i];
    if (t == 0) rowptr[NNODES] = ssum[1023];
}

__global__ __launch_bounds__(256) void k_fill(const int* __restrict__ row, const int* __restrict__ col,
    const float* __restrict__ w, const float* __restrict__ dinv,
    const int* __restrict__ rowptr, int* __restrict__ fill,
    int* __restrict__ ecol, float* __restrict__ ea)
{
    int e = blockIdx.x*256 + threadIdx.x;
    if (e >= NE) return;
    int r = row[e], c = col[e];
    int pos = rowptr[r] + atomicAdd(&fill[r], 1);
    ecol[pos] = c;
    ea[pos] = w[e] * dinv[r] * dinv[c];
}

// ---------------- pack B into MFMA fragment order (bf16) ----------------
// layout: out[((kb*NF + nb)*64 + lane)*8 + j] = B[kb*32 + 8*(lane>>4) + j][nb*16 + (lane&15)]
// mode 0: B[k][n], k<Fin, n<192: n<64 -> W[0][k][n]-W[2][k][n]; n<128 -> W[1][k][n-64]; else W[2][k][n-128]
// mode 1: B[k][n], k<192, n<256: W[k/64][k%64][n]   (W3 concat)
__global__ __launch_bounds__(256) void k_packB(const float* __restrict__ W, int Fin, int NF, int K,
    int mode, ushort* __restrict__ out)
{
    int t = blockIdx.x*256 + threadIdx.x;
    int lane = t & 63;
    int fid = t >> 6;
    if (fid >= (K/32)*NF) return;
    int kb = fid / NF, nb = fid % NF;
    int kbase = kb*32 + ((lane>>4)<<3);
    int n0 = nb*16 + (lane&15);
    #pragma unroll
    for (int j = 0; j < 8; ++j) {
        int kk = kbase + j;
        float v;
        if (mode == 0) {
            if (n0 < 64)       v = W[kk*64 + n0] - W[2*Fin*64 + kk*64 + n0];
            else if (n0 < 128) v = W[Fin*64 + kk*64 + (n0-64)];
            else               v = W[2*Fin*64 + kk*64 + (n0-128)];
        } else {
            v = W[(kk>>6)*64*256 + (kk&63)*256 + n0];
        }
        out[((long)fid*64 + lane)*8 + j] = f2b(v);
    }
}

// ---------------- MFMA GEMM: C[M,N_] = concat(A0|A1|A2)[M,K] @ Bpacked ----------------
// A row stride = Kper (elements). AF32: A is fp32 (converted in-register), else bf16.
// OUTF32: C fp32, else bf16. No LDS; B frags read from packed global (L2-hot).
template<int N_, int AF32, int OUTF32>
__global__ __launch_bounds__(256) void k_mgemm(
    const void* __restrict__ A0v, const void* __restrict__ A1v, const void* __restrict__ A2v,
    int Kper, int K, const ushort* __restrict__ Bp, void* __restrict__ Cv)
{
    const int NF = N_/16;
    int tid = threadIdx.x;
    int w = tid >> 6, l = tid & 63;
    long row_base = (long)blockIdx.x*128 + w*32;
    int lr = l & 15;
    int kg = l >> 4;
    f32x4 acc[2][NF];
    #pragma unroll
    for (int rf = 0; rf < 2; ++rf)
        #pragma unroll
        for (int nb = 0; nb < NF; ++nb) acc[rf][nb] = (f32x4){0.f,0.f,0.f,0.f};

    for (int kt = 0; kt < K; kt += 32) {
        int part = kt / Kper;
        const void* Ap = (part == 0) ? A0v : ((part == 1) ? A1v : A2v);
        int kc = kt - part*Kper;
        s8v afr[2];
        #pragma unroll
        for (int rf = 0; rf < 2; ++rf) {
            long row = row_base + rf*16 + lr;
            if (AF32) {
                const float* af = (const float*)Ap + row*(long)Kper + kc + (kg<<3);
                float4 v0 = *(const float4*)af;
                float4 v1 = *(const float4*)(af + 4);
                s8v fr;
                fr[0]=(short)f2b(v0.x); fr[1]=(short)f2b(v0.y); fr[2]=(short)f2b(v0.z); fr[3]=(short)f2b(v0.w);
                fr[4]=(short)f2b(v1.x); fr[5]=(short)f2b(v1.y); fr[6]=(short)f2b(v1.z); fr[7]=(short)f2b(v1.w);
                afr[rf] = fr;
            } else {
                afr[rf] = *(const s8v*)((const ushort*)Ap + row*(long)Kper + kc + (kg<<3));
            }
        }
        const ushort* bb = Bp + ((long)(kt>>5)*NF*64 + l)*8;
        #pragma unroll
        for (int nb = 0; nb < NF; ++nb) {
            s8v bfr = *(const s8v*)(bb + (long)nb*64*8);
            acc[0][nb] = __builtin_amdgcn_mfma_f32_16x16x32_bf16(afr[0], bfr, acc[0][nb], 0, 0, 0);
            acc[1][nb] = __builtin_amdgcn_mfma_f32_16x16x32_bf16(afr[1], bfr, acc[1][nb], 0, 0, 0);
        }
    }
    // C/D layout: col = lane&15, row = (lane>>4)*4 + i
    #pragma unroll
    for (int rf = 0; rf < 2; ++rf) {
        long r0 = row_base + rf*16 + (kg<<2);
        #pragma unroll
        for (int nb = 0; nb < NF; ++nb) {
            int cc = nb*16 + lr;
            #pragma unroll
            for (int i = 0; i < 4; ++i) {
                float v = acc[rf][nb][i];
                if (OUTF32) ((float*)Cv)[(r0+i)*N_ + cc] = v;
                else        ((ushort*)Cv)[(r0+i)*N_ + cc] = f2b(v);
            }
        }
    }
}

// ---------------- propagation (CSR gather, bf16): dst = beta*base + alpha*sum_e a[e]*src[col[e]] ----------------
__global__ __launch_bounds__(256) void k_prop(
    const int* __restrict__ rowptr, const int* __restrict__ ecol, const float* __restrict__ ea,
    const ushort* __restrict__ src, int sstride, int soff,
    const ushort* __restrict__ basep, int bstride, int boff, float beta,
    ushort* __restrict__ dst, int dstride, int doff, float alpha)
{
    int g = blockIdx.x*16 + (threadIdx.x >> 4);
    int q = threadIdx.x & 15;
    int e0 = rowptr[g], e1 = rowptr[g+1];
    f32x4 acc[4];
    #pragma unroll
    for (int b = 0; b < 4; ++b) acc[b] = (f32x4){0.f,0.f,0.f,0.f};
    for (int e = e0; e < e1; ++e) {
        int c = ecol[e];
        float a = ea[e];
        #pragma unroll
        for (int b = 0; b < 4; ++b) {
            ushort4 v = *(const ushort4*)(src + ((long)b*NNODES + c)*sstride + soff + q*4);
            acc[b][0] += a*b2f(v.x); acc[b][1] += a*b2f(v.y);
            acc[b][2] += a*b2f(v.z); acc[b][3] += a*b2f(v.w);
        }
    }
    #pragma unroll
    for (int b = 0; b < 4; ++b) {
        float r0 = alpha*acc[b][0], r1 = alpha*acc[b][1], r2 = alpha*acc[b][2], r3 = alpha*acc[b][3];
        if (basep) {
            ushort4 bb = *(const ushort4*)(basep + ((long)b*NNODES + g)*bstride + boff + q*4);
            r0 += beta*b2f(bb.x); r1 += beta*b2f(bb.y); r2 += beta*b2f(bb.z); r3 += beta*b2f(bb.w);
        }
        ushort4 o; o.x = f2b(r0); o.y = f2b(r1); o.z = f2b(r2); o.w = f2b(r3);
        *(ushort4*)(dst + ((long)b*NNODES + g)*dstride + doff + q*4) = o;
    }
}

// ---------------- instance-norm ----------------
// stats over bf16 U[:,0:64] (stride 192)
__global__ __launch_bounds__(256) void k_stats64(const ushort* __restrict__ y,
    float* __restrict__ sum, float* __restrict__ sumsq)
{
    int b = blockIdx.y;
    int c4 = (threadIdx.x & 15)*4;
    int rsub = threadIdx.x >> 4;   // 0..15
    long r0 = (long)blockIdx.x*256;
    float s0=0,s1=0,s2=0,s3=0, q0=0,q1=0,q2=0,q3=0;
    for (int i = 0; i < 16; ++i) {
        long r = r0 + rsub + i*16;
        ushort4 v = *(const ushort4*)(y + ((long)b*NNODES + r)*192 + c4);
        float f0=b2f(v.x), f1=b2f(v.y), f2=b2f(v.z), f3=b2f(v.w);
        s0+=f0; q0+=f0*f0; s1+=f1; q1+=f1*f1; s2+=f2; q2+=f2*f2; s3+=f3; q3+=f3*f3;
    }
    __shared__ float ls[16][64], lss[16][64];
    ls[rsub][c4]=s0; ls[rsub][c4+1]=s1; ls[rsub][c4+2]=s2; ls[rsub][c4+3]=s3;
    lss[rsub][c4]=q0; lss[rsub][c4+1]=q1; lss[rsub][c4+2]=q2; lss[rsub][c4+3]=q3;
    __syncthreads();
    for (int off = 8; off; off >>= 1) {
        if (rsub < off) {
            #pragma unroll
            for (int j = 0; j < 4; ++j) {
                ls[rsub][c4+j] += ls[rsub+off][c4+j];
                lss[rsub][c4+j] += lss[rsub+off][c4+j];
            }
        }
        __syncthreads();
    }
    if (rsub == 0) {
        #pragma unroll
        for (int j = 0; j < 4; ++j) {
            atomicAdd(&sum[b*256 + c4 + j], ls[0][c4+j]);
            atomicAdd(&sumsq[b*256 + c4 + j], lss[0][c4+j]);
        }
    }
}

// stats over fp32 Y[:,0:256]
__global__ __launch_bounds__(256) void k_stats256(const float* __restrict__ y,
    float* __restrict__ sum, float* __restrict__ sumsq)
{
    int b = blockIdx.y;
    int c = threadIdx.x;
    long r0 = (long)blockIdx.x*256;
    float s = 0.f, ss = 0.f;
    for (int r = 0; r < 256; ++r) {
        float v = y[((long)b*NNODES + r0 + r)*256 + c];
        s += v; ss += v*v;
    }
    atomicAdd(&sum[b*256 + c], s);
    atomicAdd(&sumsq[b*256 + c], ss);
}

__global__ __launch_bounds__(256) void k_finalize(const float* __restrict__ sum,
    const float* __restrict__ sumsq, float* __restrict__ mean, float* __restrict__ rs, int C_)
{
    int i = blockIdx.x*256 + threadIdx.x;
    if (i >= NB*256) return;
    int c = i % 256;
    if (c >= C_) return;
    float m = sum[i] / (float)NNODES;
    float v = sumsq[i] / (float)NNODES - m*m;
    mean[i] = m;
    rs[i] = rsqrtf(v + EPS);
}

// X[bn*64+c] = relu((U[bn*192+c]-mean)*rs)  (bf16 in/out)
__global__ __launch_bounds__(256) void k_normrelu(const ushort* __restrict__ U,
    const float* __restrict__ mean, const float* __restrict__ rs, ushort* __restrict__ X)
{
    long idx = (long)blockIdx.x*256 + threadIdx.x;  // MTOT*16 threads
    long bn = idx >> 4;
    int q = (int)(idx & 15);
    int b = (int)(bn / NNODES);
    ushort4 v = *(const ushort4*)(U + bn*192 + q*4);
    float4 m = *(const float4*)(mean + b*256 + q*4);
    float4 r_ = *(const float4*)(rs + b*256 + q*4);
    ushort4 o;
    o.x = f2b(fmaxf((b2f(v.x)-m.x)*r_.x, 0.f));
    o.y = f2b(fmaxf((b2f(v.y)-m.y)*r_.y, 0.f));
    o.z = f2b(fmaxf((b2f(v.z)-m.z)*r_.z, 0.f));
    o.w = f2b(fmaxf((b2f(v.w)-m.w)*r_.w, 0.f));
    *(ushort4*)(X + bn*64 + q*4) = o;
}

// Y = relu((Y-mean)*rs) + x   (in-place over d_out, fp32 [M,256])
__global__ __launch_bounds__(256) void k_final(float* __restrict__ Y,
    const float* __restrict__ x, const float* __restrict__ mean, const float* __restrict__ rs)
{
    long idx = (long)blockIdx.x*256 + threadIdx.x;  // MTOT*64 threads
    long bn = idx >> 6;
    int q = (int)(idx & 63);
    int b = (int)(bn / NNODES);
    float4 v = *(const float4*)(Y + bn*256 + q*4);
    float4 m = *(const float4*)(mean + b*256 + q*4);
    float4 r_ = *(const float4*)(rs + b*256 + q*4);
    float4 xv = *(const float4*)(x + bn*256 + q*4);
    float4 o;
    o.x = fmaxf((v.x-m.x)*r_.x, 0.f) + xv.x;
    o.y = fmaxf((v.y-m.y)*r_.y, 0.f) + xv.y;
    o.z = fmaxf((v.z-m.z)*r_.z, 0.f) + xv.z;
    o.w = fmaxf((v.w-m.w)*r_.w, 0.f) + xv.w;
    *(float4*)(Y + bn*256 + q*4) = o;
}

extern "C" void kernel_launch(void* const* d_in, const int* in_sizes, int n_in,
                              void* d_out, int out_size, void* d_ws, size_t ws_size,
                              hipStream_t stream)
{
    const float* x  = (const float*)d_in[0];
    const int*   ei = (const int*)d_in[1];
    const float* ew = (const float*)d_in[2];
    const float* W1 = (const float*)d_in[3];
    const float* W2 = (const float*)d_in[5];
    const float* W3 = (const float*)d_in[7];
    const int* row = ei;
    const int* col = ei + NE;

    // ---- workspace bump allocator (1 KiB aligned) ----
    char* p = (char*)d_ws;
    size_t used = 0;
    auto alloc = [&](size_t bytes) -> void* {
        void* r = p + used;
        used += (bytes + 1023) & ~(size_t)1023;
        return r;
    };
    float* deg   = (float*)alloc((size_t)3*NNODES*4);   // deg | cnt | fill (one memset)
    int*   cnt   = (int*)(deg + NNODES);
    int*   fillc = (int*)(deg + 2*NNODES);
    float* dinv  = (float*)alloc((size_t)NNODES*4);
    int*   rowptr= (int*)alloc((size_t)(NNODES+1)*4);
    int*   ecol  = (int*)alloc((size_t)NE*4);
    float* ea    = (float*)alloc((size_t)NE*4);
    float* stats = (float*)alloc((size_t)2*NB*256*4);   // sum | sumsq
    float* sumb  = stats;
    float* sumsq = stats + NB*256;
    float* meanb = (float*)alloc((size_t)NB*256*4);
    float* rsb   = (float*)alloc((size_t)NB*256*4);
    ushort* Bp1  = (ushort*)alloc((size_t)256*192*2);
    ushort* Bp2  = (ushort*)alloc((size_t)64*192*2);
    ushort* Bp3  = (ushort*)alloc((size_t)192*256*2);
    ushort* bufX = (ushort*)alloc((size_t)MTOT*64*2);
    ushort* T1   = (ushort*)alloc((size_t)MTOT*64*2);
    ushort* T2   = (ushort*)alloc((size_t)MTOT*64*2);
    if (ws_size < used) return;

    ushort* U = (ushort*)d_out;   // [MTOT,192] bf16 scratch for layers 1-2 (75MB < 201MB)
    float*  Y = (float*)d_out;    // [MTOT,256] fp32 final

    // ---- setup ----
    hipMemsetAsync(deg, 0, (size_t)3*NNODES*4, stream);
    k_deg_cnt<<<NE/256, 256, 0, stream>>>(row, ew, deg, cnt);
    k_dinv<<<NNODES/256, 256, 0, stream>>>(deg, dinv);
    k_scan<<<1, 1024, 0, stream>>>(cnt, rowptr);
    k_fill<<<NE/256, 256, 0, stream>>>(row, col, ew, dinv, rowptr, fillc, ecol, ea);
    k_packB<<<24, 256, 0, stream>>>(W1, 256, 12, 256, 0, Bp1);
    k_packB<<<6, 256, 0, stream>>>(W2, 64, 12, 64, 0, Bp2);
    k_packB<<<24, 256, 0, stream>>>(W3, 64, 16, 192, 1, Bp3);

    // ---- layer 1: 256 -> 64 ----
    k_mgemm<192,1,0><<<MTOT/128, 256, 0, stream>>>(x, nullptr, nullptr, 256, 256, Bp1, U);
    k_prop<<<NNODES/16, 256, 0, stream>>>(rowptr, ecol, ea, U,192,128, U,192,64, 1.f, U,192,64, -2.f);
    k_prop<<<NNODES/16, 256, 0, stream>>>(rowptr, ecol, ea, U,192,64,  U,192,0,  1.f, U,192,0,  -1.f);
    hipMemsetAsync(stats, 0, (size_t)2*NB*256*4, stream);
    k_stats64<<<dim3(NNODES/256, NB), 256, 0, stream>>>(U, sumb, sumsq);
    k_finalize<<<NB, 256, 0, stream>>>(sumb, sumsq, meanb, rsb, 64);
    k_normrelu<<<MTOT*16/256, 256, 0, stream>>>(U, meanb, rsb, bufX);

    // ---- layer 2: 64 -> 64 ----
    k_mgemm<192,0,0><<<MTOT/128, 256, 0, stream>>>(bufX, nullptr, nullptr, 64, 64, Bp2, U);
    k_prop<<<NNODES/16, 256, 0, stream>>>(rowptr, ecol, ea, U,192,128, U,192,64, 1.f, U,192,64, -2.f);
    k_prop<<<NNODES/16, 256, 0, stream>>>(rowptr, ecol, ea, U,192,64,  U,192,0,  1.f, U,192,0,  -1.f);
    hipMemsetAsync(stats, 0, (size_t)2*NB*256*4, stream);
    k_stats64<<<dim3(NNODES/256, NB), 256, 0, stream>>>(U, sumb, sumsq);
    k_finalize<<<NB, 256, 0, stream>>>(sumb, sumsq, meanb, rsb, 64);
    k_normrelu<<<MTOT*16/256, 256, 0, stream>>>(U, meanb, rsb, bufX);   // bufX = X3

    // ---- layer 3: 64 -> 256 (propagate in 64-dim input space) ----
    k_prop<<<NNODES/16, 256, 0, stream>>>(rowptr, ecol, ea, bufX,64,0, (const ushort*)nullptr,0,0, 0.f, T1,64,0, -1.f);
    k_prop<<<NNODES/16, 256, 0, stream>>>(rowptr, ecol, ea, T1,64,0, bufX,64,0, -1.f, T2,64,0, -2.f);
    k_mgemm<256,0,1><<<MTOT/128, 256, 0, stream>>>(bufX, T1, T2, 64, 192, Bp3, Y);
    hipMemsetAsync(stats, 0, (size_t)2*NB*256*4, stream);
    k_stats256<<<dim3(NNODES/256, NB), 256, 0, stream>>>(Y, sumb, sumsq);
    k_finalize<<<NB, 256, 0, stream>>>(sumb, sumsq, meanb, rsb, 256);
    k_final<<<MTOT*64/256, 256, 0, stream>>>(Y, x, meanb, rsb);
}